// Round 3
// baseline (91.659 us; speedup 1.0000x reference)
//
#include <hip/hip_runtime.h>
#include <hip/hip_bf16.h>

#define F 64
#define C 128
#define M_BLK 128
#define XSTRIDE 72   // ushorts per row = 144 B: 2-way bank aliasing (free), 16B-aligned
#define TPB_TILES 4  // tiles per persistent block

typedef __attribute__((ext_vector_type(8))) short short8;
typedef __attribute__((ext_vector_type(4))) float floatx4;
typedef __attribute__((ext_vector_type(4))) unsigned short ushort4_t;

__device__ __forceinline__ unsigned short f32_to_bf16_rne(float f) {
    unsigned int u = __builtin_bit_cast(unsigned int, f);
    unsigned int r = u + 0x7FFFu + ((u >> 16) & 1u);
    return (unsigned short)(r >> 16);
}

// plain cast — compiler lowers pairs to v_cvt_pk_bf16_f32 (m240: don't hand-write)
__device__ __forceinline__ unsigned short bf16c(float f) {
    return __builtin_bit_cast(unsigned short, __float2bfloat16(f));
}

__device__ __forceinline__ float sigmoidf(float v) {
    return 1.0f / (1.0f + __expf(-v));
}

// Zero d_out (blocks 0..Z-1) + build per-lane bf16 W fragments in d_ws (last block).
__global__ __launch_bounds__(256) void prep_kernel(
    const float* __restrict__ w, float* __restrict__ out,
    unsigned short* __restrict__ wsfrag, int out_f4)
{
    const int b = blockIdx.x;
    if (b < (int)gridDim.x - 1) {
        int idx = b * 256 + threadIdx.x;
        if (idx < out_f4) ((float4*)out)[idx] = make_float4(0.f, 0.f, 0.f, 0.f);
    } else {
        #pragma unroll
        for (int i = 0; i < 4; ++i) {
            int idx = threadIdx.x * 4 + i;           // 0..1023
            int lane = idx & 63;
            int ks   = (idx >> 6) & 1;
            int nf   = (idx >> 7) & 1;
            int wv   = idx >> 8;
            int col  = wv * 32 + nf * 16 + (lane & 15);
            int kg   = (lane >> 4) * 8;
            unsigned short* dst = wsfrag + (size_t)idx * 8;
            #pragma unroll
            for (int e = 0; e < 8; ++e) {
                int k = ks * 32 + kg + e;
                dst[e] = f32_to_bf16_rne(w[k * C + col]);
            }
        }
    }
}

__global__ __launch_bounds__(256, 3) void fused_seg_gemm(
    const float* __restrict__ x, const unsigned short* __restrict__ wsfrag,
    const int* __restrict__ seg, float* __restrict__ out)
{
    __shared__ unsigned short xlds[2][M_BLK * XSTRIDE];  // 2 x 18 KB
    __shared__ int seg_lds[2][M_BLK];

    const int tid  = threadIdx.x;
    const int lane = tid & 63;
    const int wave = tid >> 6;
    const long long tile0 = (long long)blockIdx.x * TPB_TILES;

    // ---- B fragments: 4 coalesced dwordx4 from L2-resident ws ----
    short8 bfrag[2][2];
    {
        const short8* fb = (const short8*)wsfrag;
        #pragma unroll
        for (int nf = 0; nf < 2; ++nf)
            #pragma unroll
            for (int ks = 0; ks < 2; ++ks)
                bfrag[nf][ks] = fb[((wave * 2 + nf) * 2 + ks) * 64 + lane];
    }

    float4 xr[8];
    int my_seg = 0;

    // ---- prologue: load + stage tile0 into buf 0 ----
    {
        const float4* xs = (const float4*)(x + tile0 * M_BLK * F);
        #pragma unroll
        for (int p = 0; p < 8; ++p) xr[p] = xs[tid + p * 256];
        if (tid < M_BLK) my_seg = seg[tile0 * M_BLK + tid];
        #pragma unroll
        for (int p = 0; p < 8; ++p) {
            int linear = tid + p * 256;
            int item = linear >> 4, kq = linear & 15;
            ushort4_t bv;
            bv.x = bf16c(xr[p].x); bv.y = bf16c(xr[p].y);
            bv.z = bf16c(xr[p].z); bv.w = bf16c(xr[p].w);
            *(ushort4_t*)(&xlds[0][item * XSTRIDE + kq * 4]) = bv;
        }
        if (tid < M_BLK) seg_lds[0][tid] = my_seg;
    }
    __syncthreads();

    for (int t = 0; t < TPB_TILES; ++t) {
        const int cur = t & 1;
        const bool has_next = (t + 1 < TPB_TILES);

        // ---- issue next tile's global loads NOW (hide HBM under compute) ----
        if (has_next) {
            const float4* xs = (const float4*)(x + (tile0 + t + 1) * M_BLK * F);
            #pragma unroll
            for (int p = 0; p < 8; ++p) xr[p] = xs[tid + p * 256];
            if (tid < M_BLK) my_seg = seg[(tile0 + t + 1) * M_BLK + tid];
        }

        // ---- MFMA: wave = 128 items x 32 cols, K=64 ----
        floatx4 acc[8][2];
        #pragma unroll
        for (int mf = 0; mf < 8; ++mf)
            #pragma unroll
            for (int nf = 0; nf < 2; ++nf) acc[mf][nf] = (floatx4)0.0f;

        #pragma unroll
        for (int mf = 0; mf < 8; ++mf) {
            const int row = mf * 16 + (lane & 15);
            const int k0  = (lane >> 4) * 8;
            #pragma unroll
            for (int ks = 0; ks < 2; ++ks) {
                short8 a = *(const short8*)(&xlds[cur][row * XSTRIDE + ks * 32 + k0]);
                #pragma unroll
                for (int nf = 0; nf < 2; ++nf)
                    acc[mf][nf] = __builtin_amdgcn_mfma_f32_16x16x32_bf16(
                        a, bfrag[nf][ks], acc[mf][nf], 0, 0, 0);
            }
        }

        // ---- sigmoid + segmented reduce (C/D: col=lane&15, row=(lane>>4)*4+reg) ----
        const int seg_first = seg_lds[cur][0];
        const bool uniform = (seg_first == seg_lds[cur][M_BLK - 1]);
        const int colb = wave * 32;

        if (uniform) {
            float s0 = 0.0f, s1 = 0.0f;
            #pragma unroll
            for (int mf = 0; mf < 8; ++mf)
                #pragma unroll
                for (int r = 0; r < 4; ++r) {
                    s0 += sigmoidf(acc[mf][0][r]);
                    s1 += sigmoidf(acc[mf][1][r]);
                }
            s0 += __shfl_xor(s0, 16); s0 += __shfl_xor(s0, 32);
            s1 += __shfl_xor(s1, 16); s1 += __shfl_xor(s1, 32);
            if (lane < 16)      atomicAdd(&out[seg_first * C + colb + lane], s0);
            else if (lane < 32) atomicAdd(&out[seg_first * C + colb + 16 + (lane & 15)], s1);
        } else {
            const int g = lane >> 4;
            const int col0 = colb + (lane & 15);
            int   cur_seg = seg_lds[cur][g * 4];
            float a0 = 0.0f, a1 = 0.0f;
            #pragma unroll
            for (int mf = 0; mf < 8; ++mf)
                #pragma unroll
                for (int r = 0; r < 4; ++r) {
                    int row = mf * 16 + g * 4 + r;   // monotone increasing walk
                    int sg  = seg_lds[cur][row];
                    float v0 = sigmoidf(acc[mf][0][r]);
                    float v1 = sigmoidf(acc[mf][1][r]);
                    if (sg != cur_seg) {
                        atomicAdd(&out[cur_seg * C + col0], a0);
                        atomicAdd(&out[cur_seg * C + col0 + 16], a1);
                        cur_seg = sg; a0 = v0; a1 = v1;
                    } else {
                        a0 += v0; a1 += v1;
                    }
                }
            atomicAdd(&out[cur_seg * C + col0], a0);
            atomicAdd(&out[cur_seg * C + col0 + 16], a1);
        }

        // ---- write next tile into the other buffer, then barrier ----
        if (has_next) {
            #pragma unroll
            for (int p = 0; p < 8; ++p) {
                int linear = tid + p * 256;
                int item = linear >> 4, kq = linear & 15;
                ushort4_t bv;
                bv.x = bf16c(xr[p].x); bv.y = bf16c(xr[p].y);
                bv.z = bf16c(xr[p].z); bv.w = bf16c(xr[p].w);
                *(ushort4_t*)(&xlds[cur ^ 1][item * XSTRIDE + kq * 4]) = bv;
            }
            if (tid < M_BLK) seg_lds[cur ^ 1][tid] = my_seg;
        }
        __syncthreads();
    }
}

extern "C" void kernel_launch(void* const* d_in, const int* in_sizes, int n_in,
                              void* d_out, int out_size, void* d_ws, size_t ws_size,
                              hipStream_t stream) {
    const float* x  = (const float*)d_in[0];
    const float* w  = (const float*)d_in[1];
    const int* seg  = (const int*)d_in[2];
    float* out      = (float*)d_out;

    const int n = in_sizes[0] / F;                 // 1048576
    const int ntiles = n / M_BLK;                  // 8192
    const int nblocks = ntiles / TPB_TILES;        // 2048

    const int out_f4 = out_size / 4;
    const int zblocks = (out_f4 + 255) / 256;

    prep_kernel<<<zblocks + 1, 256, 0, stream>>>(
        w, out, (unsigned short*)d_ws, out_f4);

    fused_seg_gemm<<<nblocks, 256, 0, stream>>>(
        x, (const unsigned short*)d_ws, seg, out);
}

// Round 4
// 63.860 us; speedup vs baseline: 1.4353x; 1.4353x over previous
//
#include <hip/hip_runtime.h>
#include <hip/hip_bf16.h>

#define F 64
#define C 128
#define SPAN 128          // rows per wave
#define NT (SPAN / 16)    // 8 sixteen-row MFMA tiles per wave

typedef __attribute__((ext_vector_type(8))) short short8;
typedef __attribute__((ext_vector_type(4))) float floatx4;

__device__ __forceinline__ unsigned short f32_to_bf16_rne(float f) {
    unsigned int u = __builtin_bit_cast(unsigned int, f);
    unsigned int r = u + 0x7FFFu + ((u >> 16) & 1u);
    return (unsigned short)(r >> 16);
}

// compiler lowers pairs of these to v_cvt_pk_bf16_f32 (m240)
__device__ __forceinline__ short bf16c(float f) {
    return __builtin_bit_cast(short, __float2bfloat16(f));
}

__device__ __forceinline__ float fast_sigmoid(float v) {
    // sigma(v) = 1/(1+2^(-v*log2e)); v_exp_f32 + v_rcp_f32, 2 trans + 2 valu
    float e = __builtin_amdgcn_exp2f(v * -1.44269504088896f);
    return __builtin_amdgcn_rcpf(1.0f + e);
}

// Zero d_out (blocks 0..Z-1) + build per-lane bf16 W fragments in d_ws (last block).
// Entry idx = (nf*2+ks)*64 + lane, 8 bf16 each; col = nf*16+(lane&15),
// k = ks*32 + (lane>>4)*8 + e  (same k-mapping as the A-fragment load).
__global__ __launch_bounds__(256) void prep_kernel(
    const float* __restrict__ w, float* __restrict__ out,
    unsigned short* __restrict__ wsfrag, int out_f4)
{
    const int b = blockIdx.x;
    if (b < (int)gridDim.x - 1) {
        int idx = b * 256 + threadIdx.x;
        if (idx < out_f4) ((float4*)out)[idx] = make_float4(0.f, 0.f, 0.f, 0.f);
    } else {
        #pragma unroll
        for (int i = 0; i < 4; ++i) {
            int idx = threadIdx.x * 4 + i;            // 0..1023
            int lane = idx & 63;
            int ks   = (idx >> 6) & 1;
            int nf   = idx >> 7;                      // 0..7
            int col  = nf * 16 + (lane & 15);
            int kg   = (lane >> 4) * 8;
            unsigned short* dst = wsfrag + (size_t)idx * 8;
            #pragma unroll
            for (int e = 0; e < 8; ++e) {
                int k = ks * 32 + kg + e;
                dst[e] = f32_to_bf16_rne(w[k * C + col]);
            }
        }
    }
}

// LDS-free: each wave streams 128 rows as 8 x 16-row tiles, loading MFMA
// A-fragments straight from global (a wave's 64x16B = one contiguous 4KB tile),
// W held in registers, per-column bag sums carried in registers across tiles.
__global__ __launch_bounds__(256, 3) void fused_seg_gemm(
    const float* __restrict__ x, const unsigned short* __restrict__ wsfrag,
    const int* __restrict__ seg, float* __restrict__ out)
{
    const int tid  = threadIdx.x;
    const int lane = tid & 63;
    const int wave = tid >> 6;
    const int l15  = lane & 15;
    const int g    = lane >> 4;
    const long long base = ((long long)blockIdx.x * 4 + wave) * SPAN;

    // ---- W fragments: 16 coalesced dwordx4 from L2-resident ws, kept in regs ----
    short8 bfrag[8][2];
    {
        const short8* fb = (const short8*)wsfrag;
        #pragma unroll
        for (int nf = 0; nf < 8; ++nf)
            #pragma unroll
            for (int ks = 0; ks < 2; ++ks)
                bfrag[nf][ks] = fb[(nf * 2 + ks) * 64 + lane];
    }

    // A-fragment float4 index for tile t: fi + t*256 (+1 hi, +8 ks1)
    const float4* xp = (const float4*)(x + base * F);
    const int fi = l15 * 16 + g * 2;

    // prologue loads (tile 0)
    float4 c0 = xp[fi], c1 = xp[fi + 1], c2 = xp[fi + 8], c3 = xp[fi + 9];
    int s = seg[base + l15];

    float runsum[8];
    #pragma unroll
    for (int nf = 0; nf < 8; ++nf) runsum[nf] = 0.0f;
    int cur_seg = -1;

    auto flush = [&]() {
        if (cur_seg >= 0) {
            #pragma unroll
            for (int nf = 0; nf < 8; ++nf) {
                float v = runsum[nf];
                v += __shfl_xor(v, 16);
                v += __shfl_xor(v, 32);
                if (lane < 16) atomicAdd(&out[cur_seg * C + nf * 16 + lane], v);
                runsum[nf] = 0.0f;
            }
        }
        cur_seg = -1;
    };

    #pragma unroll 2
    for (int t = 0; t < NT; ++t) {
        // ---- prefetch tile t+1 (independent, hides HBM under compute) ----
        float4 n0, n1, n2, n3; int ns = s;
        const bool more = (t + 1 < NT);
        if (more) {
            int nfi = fi + (t + 1) * 256;
            n0 = xp[nfi]; n1 = xp[nfi + 1]; n2 = xp[nfi + 8]; n3 = xp[nfi + 9];
            ns = seg[base + (t + 1) * 16 + l15];
        }

        // ---- convert to bf16 A-fragments ----
        short8 a0, a1;
        a0[0] = bf16c(c0.x); a0[1] = bf16c(c0.y); a0[2] = bf16c(c0.z); a0[3] = bf16c(c0.w);
        a0[4] = bf16c(c1.x); a0[5] = bf16c(c1.y); a0[6] = bf16c(c1.z); a0[7] = bf16c(c1.w);
        a1[0] = bf16c(c2.x); a1[1] = bf16c(c2.y); a1[2] = bf16c(c2.z); a1[3] = bf16c(c2.w);
        a1[4] = bf16c(c3.x); a1[5] = bf16c(c3.y); a1[6] = bf16c(c3.z); a1[7] = bf16c(c3.w);

        // ---- 16 MFMAs: 16 rows x 128 cols, K=64 ----
        floatx4 acc[8];
        #pragma unroll
        for (int nf = 0; nf < 8; ++nf) {
            acc[nf] = (floatx4)0.0f;
            acc[nf] = __builtin_amdgcn_mfma_f32_16x16x32_bf16(a0, bfrag[nf][0], acc[nf], 0, 0, 0);
            acc[nf] = __builtin_amdgcn_mfma_f32_16x16x32_bf16(a1, bfrag[nf][1], acc[nf], 0, 0, 0);
        }

        // ---- sigmoid + segmented accumulate ----
        // C/D layout (m89): col = nf*16 + l15, tile-row = g*4 + r
        const int u0 = __shfl(s, 0), u15 = __shfl(s, 15);
        if (u0 == u15) {                       // uniform tile (~94%), wave-uniform branch
            if (u0 != cur_seg) { flush(); cur_seg = u0; }
            #pragma unroll
            for (int nf = 0; nf < 8; ++nf)
                #pragma unroll
                for (int r = 0; r < 4; ++r)
                    runsum[nf] += fast_sigmoid(acc[nf][r]);
        } else {                               // boundary tile: per-lane monotone walk
            flush();
            const int sr0 = __shfl(s, g * 4 + 0), sr1 = __shfl(s, g * 4 + 1);
            const int sr2 = __shfl(s, g * 4 + 2), sr3 = __shfl(s, g * 4 + 3);
            #pragma unroll
            for (int nf = 0; nf < 8; ++nf) {
                const int col = nf * 16 + l15;
                float run = fast_sigmoid(acc[nf][0]);
                int   rs  = sr0;
                float v;
                v = fast_sigmoid(acc[nf][1]);
                if (sr1 != rs) { atomicAdd(&out[rs * C + col], run); rs = sr1; run = v; } else run += v;
                v = fast_sigmoid(acc[nf][2]);
                if (sr2 != rs) { atomicAdd(&out[rs * C + col], run); rs = sr2; run = v; } else run += v;
                v = fast_sigmoid(acc[nf][3]);
                if (sr3 != rs) { atomicAdd(&out[rs * C + col], run); rs = sr3; run = v; } else run += v;
                atomicAdd(&out[rs * C + col], run);
            }
        }

        if (more) { c0 = n0; c1 = n1; c2 = n2; c3 = n3; s = ns; }
    }
    flush();
}

extern "C" void kernel_launch(void* const* d_in, const int* in_sizes, int n_in,
                              void* d_out, int out_size, void* d_ws, size_t ws_size,
                              hipStream_t stream) {
    const float* x  = (const float*)d_in[0];
    const float* w  = (const float*)d_in[1];
    const int* seg  = (const int*)d_in[2];
    float* out      = (float*)d_out;

    const int n = in_sizes[0] / F;                    // 1048576
    const int nblocks = n / (4 * SPAN);               // 2048 blocks x 4 waves x 128 rows

    const int out_f4 = out_size / 4;
    const int zblocks = (out_f4 + 255) / 256;

    prep_kernel<<<zblocks + 1, 256, 0, stream>>>(
        w, out, (unsigned short*)d_ws, out_f4);

    fused_seg_gemm<<<nblocks, 256, 0, stream>>>(
        x, (const unsigned short*)d_ws, seg, out);
}